// Round 16
// baseline (73.223 us; speedup 1.0000x reference)
//
#include <hip/hip_runtime.h>
#include <hip/hip_bf16.h>

typedef __bf16 bf16_t;
typedef __bf16 bf16x8 __attribute__((ext_vector_type(8)));
typedef __bf16 bf16x4 __attribute__((ext_vector_type(4)));
typedef float  f32x4  __attribute__((ext_vector_type(4)));

#define MFMA_BF16(A, B, C) __builtin_amdgcn_mfma_f32_16x16x32_bf16((A), (B), (C), 0, 0, 0)

#define BATCH 8
#define SEQ   2048
#define EMB   1024
#define HEAD  64

typedef __attribute__((address_space(3))) void as3_void;
typedef const __attribute__((address_space(1))) void as1_void;
#define GLOAD_LDS16(g, l) \
  __builtin_amdgcn_global_load_lds((as1_void*)(g), (as3_void*)(l), 16, 0, 0)

// ---------------------------------------------------------------------------
// Kernel 0: W [1024][64] fp32 x3 -> WT bf16 [192][1024] (transposed).
// Wq gets scale log2(e)/32 folded in (attn uses exp2).
// ---------------------------------------------------------------------------
__global__ __launch_bounds__(256) void wtrans_kernel(
    const float* __restrict__ Wq, const float* __restrict__ Wk,
    const float* __restrict__ Wv, bf16_t* __restrict__ WT)
{
  __shared__ float tile[64][65];
  const int m  = blockIdx.x >> 4;
  const int kt = blockIdx.x & 15;
  const float* W = (m == 0) ? Wq : (m == 1) ? Wk : Wv;
  const float scale = (m == 0) ? 0.045084219f : 1.0f;   // log2(e)/32
  const int k0 = kt * 64;

  #pragma unroll
  for (int i = 0; i < 16; ++i) {
    int idx = i * 256 + threadIdx.x;
    int kk = idx >> 6, n = idx & 63;
    tile[kk][n] = W[(size_t)(k0 + kk) * HEAD + n];
  }
  __syncthreads();
  #pragma unroll
  for (int i = 0; i < 16; ++i) {
    int idx = i * 256 + threadIdx.x;
    int n = idx >> 6, kk = idx & 63;
    WT[((size_t)m * HEAD + n) * EMB + k0 + kk] = (bf16_t)(tile[kk][n] * scale);
  }
}

// ---------------------------------------------------------------------------
// Kernel 1: qkv v9 (UNCHANGED — measured 18.5 µs, stable R9-R15).
// ---------------------------------------------------------------------------
#define A_BYTES 16384     // 64 rows x 256 B (fp32, BK=64)
#define B_BYTES 24576     // 192 rows x 128 B (bf16, BK=64)
#define BUF_BYTES 40960

__global__ __launch_bounds__(512, 1) void qkv_kernel(
    const float* __restrict__ x, const bf16_t* __restrict__ WT,
    bf16_t* __restrict__ qo, bf16_t* __restrict__ ko, bf16_t* __restrict__ vT)
{
  __shared__ char lds[4 * BUF_BYTES];            // 160 KB

  const int tid  = threadIdx.x;
  const int lane = tid & 63;
  const int wave = tid >> 6;                     // 0..7
  const int l15 = lane & 15, l4 = lane >> 4;
  const int wm = wave >> 2, wn = wave & 3;
  const int rowbase = blockIdx.x * 64;
  const int phase = (blockIdx.x >> 3) & 15;      // k-stagger (sum order-free)

  const int a_rsub = lane >> 4;
  const int b_rsub = lane >> 3;
  const int b_koff = ((lane & 7) * 16) ^ (b_rsub << 4);

  const int aswz = (l15 & 7) << 5;               // read-side XORs (row&7==l15&7)
  const int bswz = (l15 & 7) << 4;

  f32x4 acc[2][3];
  #pragma unroll
  for (int m = 0; m < 2; ++m)
    #pragma unroll
    for (int n = 0; n < 3; ++n) acc[m][n] = (f32x4){0.f, 0.f, 0.f, 0.f};

#define STAGE(t)                                                               \
  {                                                                            \
    char* buf = lds + ((t) & 3) * BUF_BYTES;                                   \
    const int tp = ((t) + phase) & 15;                                         \
    _Pragma("unroll")                                                          \
    for (int j = 0; j < 2; ++j) {                                              \
      const int g = 2 * wave + j;                                              \
      const int koff = (l15 * 16) ^ ((((j) << 2) | a_rsub) << 5);              \
      const char* src = (const char*)x + (size_t)(rowbase + 4 * g + a_rsub)    \
                        * 4096 + (size_t)tp * 256 + koff;                      \
      GLOAD_LDS16(src, buf + g * 1024);                                        \
    }                                                                          \
    _Pragma("unroll")                                                          \
    for (int j = 0; j < 3; ++j) {                                              \
      const int g = 3 * wave + j;                                              \
      const char* src = (const char*)WT + (size_t)(8 * g + b_rsub) * 2048      \
                        + (size_t)tp * 128 + b_koff;                           \
      GLOAD_LDS16(src, buf + A_BYTES + g * 1024);                              \
    }                                                                          \
  }

#define COMPUTE(t)                                                             \
  {                                                                            \
    const char* Ab = lds + ((t) & 3) * BUF_BYTES;                              \
    const char* Bb = Ab + A_BYTES;                                             \
    _Pragma("unroll")                                                          \
    for (int ks = 0; ks < 2; ++ks) {                                           \
      bf16x8 afr[2];                                                           \
      _Pragma("unroll")                                                        \
      for (int m = 0; m < 2; ++m) {                                            \
        const int R = wm * 32 + m * 16 + l15;                                  \
        const char* rp = Ab + R * 256 + ((ks * 128 + l4 * 32) ^ aswz);         \
        f32x4 p0 = *(const f32x4*)(rp);                                        \
        f32x4 p1 = *(const f32x4*)(rp + 16);                                   \
        bf16x8 a;                                                              \
        a[0] = (bf16_t)p0.x; a[1] = (bf16_t)p0.y;                              \
        a[2] = (bf16_t)p0.z; a[3] = (bf16_t)p0.w;                              \
        a[4] = (bf16_t)p1.x; a[5] = (bf16_t)p1.y;                              \
        a[6] = (bf16_t)p1.z; a[7] = (bf16_t)p1.w;                              \
        afr[m] = a;                                                            \
      }                                                                        \
      _Pragma("unroll")                                                        \
      for (int n = 0; n < 3; ++n) {                                            \
        const int Rb = wn * 48 + n * 16 + l15;                                 \
        bf16x8 b = *(const bf16x8*)(Bb + Rb * 128 + ((ks * 64 + l4 * 16) ^ bswz)); \
        acc[0][n] = MFMA_BF16(afr[0], b, acc[0][n]);                           \
        acc[1][n] = MFMA_BF16(afr[1], b, acc[1][n]);                           \
      }                                                                        \
    }                                                                          \
  }

  STAGE(0); STAGE(1); STAGE(2);
  asm volatile("s_waitcnt vmcnt(10)" ::: "memory");
  __builtin_amdgcn_s_barrier();

  for (int t = 0; t < 13; ++t) {
    COMPUTE(t);
    STAGE(t + 3);
    asm volatile("s_waitcnt vmcnt(10)" ::: "memory");
    __builtin_amdgcn_s_barrier();
  }
  COMPUTE(13);
  asm volatile("s_waitcnt vmcnt(5)" ::: "memory");
  __builtin_amdgcn_s_barrier();
  COMPUTE(14);
  asm volatile("s_waitcnt vmcnt(0)" ::: "memory");
  __builtin_amdgcn_s_barrier();
  COMPUTE(15);
#undef STAGE
#undef COMPUTE

  #pragma unroll
  for (int n = 0; n < 3; ++n) {
    const int col = wn * 48 + n * 16;
    #pragma unroll
    for (int m = 0; m < 2; ++m) {
      const int r0 = rowbase + wm * 32 + m * 16 + l4 * 4;
      if (col < 64) {
        #pragma unroll
        for (int i = 0; i < 4; ++i)
          qo[(size_t)(r0 + i) * HEAD + col + l15] = (bf16_t)acc[m][n][i];
      } else if (col < 128) {
        #pragma unroll
        for (int i = 0; i < 4; ++i)
          ko[(size_t)(r0 + i) * HEAD + col - 64 + l15] = (bf16_t)acc[m][n][i];
      } else {
        const int h = col - 128 + l15;
        bf16x4 pk;
        #pragma unroll
        for (int i = 0; i < 4; ++i) pk[i] = (bf16_t)acc[m][n][i];
        *(bf16x4*)(vT + ((size_t)(r0 >> 11) * HEAD + h) * SEQ + (r0 & 2047)) = pk;
      }
    }
  }
}

// ---------------------------------------------------------------------------
// Kernel 2: attn v11 — QUAD blocks + qkv-v9-style K DMA ring.
// Block = strips 4u..4u+3 (ALL have ntiles = u+1). Wave w owns strip 4u+w
// completely -> per-wave (o,lsum) are final: NO cross-wave reduce at all.
// All 4 waves consume the SAME K tile per step -> K staged once per step
// via global_load_lds ring-3 (8 KB/step, 2 instrs/wave), counted vmcnt(2),
// raw s_barrier (the only pipeline structure hipcc provably keeps).
// V direct from L2, issued before exp, consumed after (latency hidden).
// Per-wave FIFO at the wait: [V(t) 8][stage(t+2) 2] -> vmcnt(2) drains
// V(t)+stage(t+1) in steady state AND tails. Grid 256 = 1 block/CU.
// ---------------------------------------------------------------------------
__global__ __launch_bounds__(256) void attn_kernel(
    const bf16_t* __restrict__ q, const bf16_t* __restrict__ k,
    const bf16_t* __restrict__ vT, float* __restrict__ out)
{
  __shared__ char kbuf[3][8192];       // ring-3 K tiles (64 rows x 128 B)
  __shared__ bf16_t P[4][16][72];      // per-wave P (pitch 72)
  const int lane = threadIdx.x & 63;
  const int wave = threadIdx.x >> 6;       // 0..3
  const int l15 = lane & 15, l4 = lane >> 4;
  const int batch = blockIdx.x & 7;        // one batch per XCD cohort
  const int u = (int)(blockIdx.x >> 3);    // 0..31
  const int strip = 4 * u + wave;          // this wave's strip
  const int qrow  = strip * 16;
  const int ntiles = u + 1;                // same for all 4 waves

  const bf16_t* kb = k  + (size_t)batch * SEQ * HEAD;
  const bf16_t* vb = vT + (size_t)batch * HEAD * SEQ;
  const bf16_t* qb = q  + ((size_t)batch * SEQ + qrow) * HEAD;

  const bf16x8 aq0 = *(const bf16x8*)(qb + (size_t)l15 * HEAD + l4 * 8);
  const bf16x8 aq1 = *(const bf16x8*)(qb + (size_t)l15 * HEAD + 32 + l4 * 8);

  // K DMA mapping (qkv-v9 proven): instr g covers rows 8g..8g+7; lane ->
  // row 8g+(l>>3), dest (l&7)*16 in 128B row; source pre-XORed (row&7)<<4.
  const int b_rsub = lane >> 3;
  const int b_koff = ((lane & 7) * 16) ^ (b_rsub << 4);
  const int kswz = (l15 & 7) << 4;         // read-side XOR (row&7 == l15&7)

#define KSTAGE(t)                                                              \
  {                                                                            \
    char* buf = kbuf[(t) % 3];                                                 \
    _Pragma("unroll")                                                          \
    for (int j = 0; j < 2; ++j) {                                              \
      const int g = 2 * wave + j;                                              \
      const char* src = (const char*)kb + (size_t)((t) * 64 + 8 * g + b_rsub)  \
                        * 128 + b_koff;                                        \
      GLOAD_LDS16(src, buf + g * 1024);                                        \
    }                                                                          \
  }

  f32x4 o[4];
  #pragma unroll
  for (int i = 0; i < 4; ++i) o[i] = (f32x4){0.f, 0.f, 0.f, 0.f};
  float lsum[4] = {0.f, 0.f, 0.f, 0.f};

  // prologue: 2 tiles in flight (tile 1 always in-bounds: SEQ rows >= 128)
  KSTAGE(0); KSTAGE(1);
  asm volatile("s_waitcnt vmcnt(2)" ::: "memory");   // tile 0 landed
  __builtin_amdgcn_s_barrier();

  for (int t = 0; t < ntiles; ++t) {
    const int kv0 = t * 64;
    const char* Kb = kbuf[t % 3];

    // --- S = Q K^T, K from LDS (prefetched; ~120cy not ~400) ---
    f32x4 s[4];
    #pragma unroll
    for (int nf = 0; nf < 4; ++nf) s[nf] = (f32x4){0.f, 0.f, 0.f, 0.f};
    __builtin_amdgcn_s_setprio(1);
    #pragma unroll
    for (int nf = 0; nf < 4; ++nf) {
      const char* kr = (const char*)Kb + (nf * 16 + l15) * 128;
      bf16x8 b0 = *(const bf16x8*)(kr + ((l4 * 16) ^ kswz));
      bf16x8 b1 = *(const bf16x8*)(kr + ((64 + l4 * 16) ^ kswz));
      s[nf] = MFMA_BF16(aq0, b0, s[nf]);
      s[nf] = MFMA_BF16(aq1, b1, s[nf]);
    }
    __builtin_amdgcn_s_setprio(0);

    // V issued early (consumed after exp -> L2 latency hidden)
    bf16x8 v0[4], v1[4];
    #pragma unroll
    for (int nf = 0; nf < 4; ++nf) {
      const bf16_t* vp = vb + (size_t)(nf * 16 + l15) * SEQ + kv0 + l4 * 8;
      v0[nf] = *(const bf16x8*)vp;
      v1[nf] = *(const bf16x8*)(vp + 32);
    }

    // stage K(t+2) (stays in flight across the barrier)
    if (t + 2 < ntiles) KSTAGE(t + 2);

    // --- P = exp2(S), causal mask on diagonal tile ---
    const bool diag = (t == ntiles - 1);
    #pragma unroll
    for (int nf = 0; nf < 4; ++nf) {
      #pragma unroll
      for (int i2 = 0; i2 < 4; ++i2) {
        float e = exp2f(s[nf][i2]);
        if (diag) {
          const int col = kv0 + nf * 16 + l15;
          const int row = qrow + l4 * 4 + i2;
          e = (col <= row) ? e : 0.f;
        }
        lsum[i2] += e;
        P[wave][l4 * 4 + i2][nf * 16 + l15] = (bf16_t)e;
      }
    }

    bf16x8 ap0 = *(const bf16x8*)&P[wave][l15][l4 * 8];
    bf16x8 ap1 = *(const bf16x8*)&P[wave][l15][32 + l4 * 8];

    // V(t) + K(t+1) landed; K(t+2) may remain in flight
    asm volatile("s_waitcnt vmcnt(2)" ::: "memory");

    __builtin_amdgcn_s_setprio(1);
    #pragma unroll
    for (int nf = 0; nf < 4; ++nf) {
      o[nf] = MFMA_BF16(ap0, v0[nf], o[nf]);
      o[nf] = MFMA_BF16(ap1, v1[nf], o[nf]);
    }
    __builtin_amdgcn_s_setprio(0);

    __builtin_amdgcn_s_barrier();    // ring WAR: K(t+3) may overwrite buf[t%3]
  }
#undef KSTAGE

  // --- epilogue: per-wave row-sums (shfl) + normalize + store; no LDS ---
  #pragma unroll
  for (int i = 0; i < 4; ++i) {
    float v = lsum[i];
    v += __shfl_xor(v, 1);
    v += __shfl_xor(v, 2);
    v += __shfl_xor(v, 4);
    v += __shfl_xor(v, 8);
    lsum[i] = 1.0f / v;
  }
  float* ob = out + ((size_t)batch * SEQ + qrow) * HEAD;
  #pragma unroll
  for (int nf = 0; nf < 4; ++nf)
    #pragma unroll
    for (int i = 0; i < 4; ++i)
      ob[(size_t)(l4 * 4 + i) * HEAD + nf * 16 + l15] = o[nf][i] * lsum[i];
}

// ---------------------------------------------------------------------------
extern "C" void kernel_launch(void* const* d_in, const int* in_sizes, int n_in,
                              void* d_out, int out_size, void* d_ws, size_t ws_size,
                              hipStream_t stream)
{
  const float* x  = (const float*)d_in[0];
  const float* Wq = (const float*)d_in[1];
  const float* Wk = (const float*)d_in[2];
  const float* Wv = (const float*)d_in[3];
  float* out = (float*)d_out;

  const size_t SZ_QKV = (size_t)BATCH * SEQ * HEAD * sizeof(bf16_t);   // 2 MiB
  if (ws_size < 3 * SZ_QKV + (size_t)192 * EMB * sizeof(bf16_t)) return;
  char* ws = (char*)d_ws;
  bf16_t* qo = (bf16_t*)(ws);
  bf16_t* ko = (bf16_t*)(ws + SZ_QKV);
  bf16_t* vT = (bf16_t*)(ws + 2 * SZ_QKV);
  bf16_t* WT = (bf16_t*)(ws + 3 * SZ_QKV);

  wtrans_kernel<<<dim3(48),  dim3(256), 0, stream>>>(Wq, Wk, Wv, WT);
  qkv_kernel  <<<dim3(256), dim3(512), 0, stream>>>(x, WT, qo, ko, vT);
  attn_kernel <<<dim3(256), dim3(256), 0, stream>>>(qo, ko, vT, out);
}

// Round 17
// 48.055 us; speedup vs baseline: 1.5237x; 1.5237x over previous
//
#include <hip/hip_runtime.h>
#include <hip/hip_bf16.h>

typedef __bf16 bf16_t;
typedef __bf16 bf16x8 __attribute__((ext_vector_type(8)));
typedef __bf16 bf16x4 __attribute__((ext_vector_type(4)));
typedef float  f32x4  __attribute__((ext_vector_type(4)));

#define MFMA_BF16(A, B, C) __builtin_amdgcn_mfma_f32_16x16x32_bf16((A), (B), (C), 0, 0, 0)

#define BATCH 8
#define SEQ   2048
#define EMB   1024
#define HEAD  64

typedef __attribute__((address_space(3))) void as3_void;
typedef const __attribute__((address_space(1))) void as1_void;
#define GLOAD_LDS16(g, l) \
  __builtin_amdgcn_global_load_lds((as1_void*)(g), (as3_void*)(l), 16, 0, 0)

// ---------------------------------------------------------------------------
// Kernel 0: W [1024][64] fp32 x3 -> WT bf16 [192][1024] (transposed).
// Wq gets scale log2(e)/32 folded in (attn uses exp2).
// ---------------------------------------------------------------------------
__global__ __launch_bounds__(256) void wtrans_kernel(
    const float* __restrict__ Wq, const float* __restrict__ Wk,
    const float* __restrict__ Wv, bf16_t* __restrict__ WT)
{
  __shared__ float tile[64][65];
  const int m  = blockIdx.x >> 4;
  const int kt = blockIdx.x & 15;
  const float* W = (m == 0) ? Wq : (m == 1) ? Wk : Wv;
  const float scale = (m == 0) ? 0.045084219f : 1.0f;   // log2(e)/32
  const int k0 = kt * 64;

  #pragma unroll
  for (int i = 0; i < 16; ++i) {
    int idx = i * 256 + threadIdx.x;
    int kk = idx >> 6, n = idx & 63;
    tile[kk][n] = W[(size_t)(k0 + kk) * HEAD + n];
  }
  __syncthreads();
  #pragma unroll
  for (int i = 0; i < 16; ++i) {
    int idx = i * 256 + threadIdx.x;
    int n = idx >> 6, kk = idx & 63;
    WT[((size_t)m * HEAD + n) * EMB + k0 + kk] = (bf16_t)(tile[kk][n] * scale);
  }
}

// ---------------------------------------------------------------------------
// Kernel 1: qkv v9 (UNCHANGED — measured 18.5 µs, stable R9-R15).
// BM=64 x N=192 x BK=64, 256 blocks (1/CU), 8 waves (2m x 4n), full K.
// Ring-4 x 40KB (160KB LDS), counted vmcnt(10), raw s_barrier; A/B both
// XOR-swizzled via pre-swizzled glds source (rule #21); k-phase stagger.
// ---------------------------------------------------------------------------
#define A_BYTES 16384     // 64 rows x 256 B (fp32, BK=64)
#define B_BYTES 24576     // 192 rows x 128 B (bf16, BK=64)
#define BUF_BYTES 40960

__global__ __launch_bounds__(512, 1) void qkv_kernel(
    const float* __restrict__ x, const bf16_t* __restrict__ WT,
    bf16_t* __restrict__ qo, bf16_t* __restrict__ ko, bf16_t* __restrict__ vT)
{
  __shared__ char lds[4 * BUF_BYTES];            // 160 KB

  const int tid  = threadIdx.x;
  const int lane = tid & 63;
  const int wave = tid >> 6;                     // 0..7
  const int l15 = lane & 15, l4 = lane >> 4;
  const int wm = wave >> 2, wn = wave & 3;
  const int rowbase = blockIdx.x * 64;
  const int phase = (blockIdx.x >> 3) & 15;      // k-stagger (sum order-free)

  const int a_rsub = lane >> 4;
  const int b_rsub = lane >> 3;
  const int b_koff = ((lane & 7) * 16) ^ (b_rsub << 4);

  const int aswz = (l15 & 7) << 5;               // read-side XORs (row&7==l15&7)
  const int bswz = (l15 & 7) << 4;

  f32x4 acc[2][3];
  #pragma unroll
  for (int m = 0; m < 2; ++m)
    #pragma unroll
    for (int n = 0; n < 3; ++n) acc[m][n] = (f32x4){0.f, 0.f, 0.f, 0.f};

#define STAGE(t)                                                               \
  {                                                                            \
    char* buf = lds + ((t) & 3) * BUF_BYTES;                                   \
    const int tp = ((t) + phase) & 15;                                         \
    _Pragma("unroll")                                                          \
    for (int j = 0; j < 2; ++j) {                                              \
      const int g = 2 * wave + j;                                              \
      const int koff = (l15 * 16) ^ ((((j) << 2) | a_rsub) << 5);              \
      const char* src = (const char*)x + (size_t)(rowbase + 4 * g + a_rsub)    \
                        * 4096 + (size_t)tp * 256 + koff;                      \
      GLOAD_LDS16(src, buf + g * 1024);                                        \
    }                                                                          \
    _Pragma("unroll")                                                          \
    for (int j = 0; j < 3; ++j) {                                              \
      const int g = 3 * wave + j;                                              \
      const char* src = (const char*)WT + (size_t)(8 * g + b_rsub) * 2048      \
                        + (size_t)tp * 128 + b_koff;                           \
      GLOAD_LDS16(src, buf + A_BYTES + g * 1024);                              \
    }                                                                          \
  }

#define COMPUTE(t)                                                             \
  {                                                                            \
    const char* Ab = lds + ((t) & 3) * BUF_BYTES;                              \
    const char* Bb = Ab + A_BYTES;                                             \
    _Pragma("unroll")                                                          \
    for (int ks = 0; ks < 2; ++ks) {                                           \
      bf16x8 afr[2];                                                           \
      _Pragma("unroll")                                                        \
      for (int m = 0; m < 2; ++m) {                                            \
        const int R = wm * 32 + m * 16 + l15;                                  \
        const char* rp = Ab + R * 256 + ((ks * 128 + l4 * 32) ^ aswz);         \
        f32x4 p0 = *(const f32x4*)(rp);                                        \
        f32x4 p1 = *(const f32x4*)(rp + 16);                                   \
        bf16x8 a;                                                              \
        a[0] = (bf16_t)p0.x; a[1] = (bf16_t)p0.y;                              \
        a[2] = (bf16_t)p0.z; a[3] = (bf16_t)p0.w;                              \
        a[4] = (bf16_t)p1.x; a[5] = (bf16_t)p1.y;                              \
        a[6] = (bf16_t)p1.z; a[7] = (bf16_t)p1.w;                              \
        afr[m] = a;                                                            \
      }                                                                        \
      _Pragma("unroll")                                                        \
      for (int n = 0; n < 3; ++n) {                                            \
        const int Rb = wn * 48 + n * 16 + l15;                                 \
        bf16x8 b = *(const bf16x8*)(Bb + Rb * 128 + ((ks * 64 + l4 * 16) ^ bswz)); \
        acc[0][n] = MFMA_BF16(afr[0], b, acc[0][n]);                           \
        acc[1][n] = MFMA_BF16(afr[1], b, acc[1][n]);                           \
      }                                                                        \
    }                                                                          \
  }

  STAGE(0); STAGE(1); STAGE(2);
  asm volatile("s_waitcnt vmcnt(10)" ::: "memory");
  __builtin_amdgcn_s_barrier();

  for (int t = 0; t < 13; ++t) {
    COMPUTE(t);
    STAGE(t + 3);
    asm volatile("s_waitcnt vmcnt(10)" ::: "memory");
    __builtin_amdgcn_s_barrier();
  }
  COMPUTE(13);
  asm volatile("s_waitcnt vmcnt(5)" ::: "memory");
  __builtin_amdgcn_s_barrier();
  COMPUTE(14);
  asm volatile("s_waitcnt vmcnt(0)" ::: "memory");
  __builtin_amdgcn_s_barrier();
  COMPUTE(15);
#undef STAGE
#undef COMPUTE

  #pragma unroll
  for (int n = 0; n < 3; ++n) {
    const int col = wn * 48 + n * 16;
    #pragma unroll
    for (int m = 0; m < 2; ++m) {
      const int r0 = rowbase + wm * 32 + m * 16 + l4 * 4;
      if (col < 64) {
        #pragma unroll
        for (int i = 0; i < 4; ++i)
          qo[(size_t)(r0 + i) * HEAD + col + l15] = (bf16_t)acc[m][n][i];
      } else if (col < 128) {
        #pragma unroll
        for (int i = 0; i < 4; ++i)
          ko[(size_t)(r0 + i) * HEAD + col - 64 + l15] = (bf16_t)acc[m][n][i];
      } else {
        const int h = col - 128 + l15;
        bf16x4 pk;
        #pragma unroll
        for (int i = 0; i < 4; ++i) pk[i] = (bf16_t)acc[m][n][i];
        *(bf16x4*)(vT + ((size_t)(r0 >> 11) * HEAD + h) * SEQ + (r0 & 2047)) = pk;
      }
    }
  }
}

// ---------------------------------------------------------------------------
// Kernel 2: attn v10 RESTORED (best measured: totals 48.35/48.43 in R13/R15).
// v11's quad-block K-ring failed (1 wave/SIMD + imbalance: 51 µs measured,
// occupancy 5.6%) — the ring skeleton needs >=2 independent blocks/CU and
// uniform work; attn's triangular workload has neither.
// 4-wave dual-strip shared-K/V + complement-pair balance + double-P
// buffers + V-loads between expA/expB + no VGPR cap.
// ---------------------------------------------------------------------------
__global__ __launch_bounds__(256) void attn_kernel(
    const bf16_t* __restrict__ q, const bf16_t* __restrict__ k,
    const bf16_t* __restrict__ vT, float* __restrict__ out)
{
  __shared__ bf16_t P[4][2][16][72];   // 18.4 KB (double-buffered per wave)
  __shared__ float olds[4][16][68];    // 17.4 KB
  __shared__ float lsums[4][16];
  const int lane = threadIdx.x & 63;
  const int wave = threadIdx.x >> 6;       // 0..3
  const int l15 = lane & 15, l4 = lane >> 4;
  const int batch = blockIdx.x & 7;
  const int idx = (int)(blockIdx.x >> 3);  // 0..63
  const int u = (blockIdx.x < 256) ? idx : (95 - idx);  // complement pairing
  const int qrowA = u * 32;                // strip 2u
  const int qrowB = u * 32 + 16;           // strip 2u+1
  const int ntiles = (u >> 1) + 1;         // identical for both strips

  const bf16_t* kb = k  + (size_t)batch * SEQ * HEAD;
  const bf16_t* vb = vT + (size_t)batch * HEAD * SEQ;
  const bf16_t* qbA = q + ((size_t)batch * SEQ + qrowA) * HEAD;
  const bf16_t* qbB = q + ((size_t)batch * SEQ + qrowB) * HEAD;

  const bf16x8 aqA0 = *(const bf16x8*)(qbA + (size_t)l15 * HEAD + l4 * 8);
  const bf16x8 aqA1 = *(const bf16x8*)(qbA + (size_t)l15 * HEAD + 32 + l4 * 8);
  const bf16x8 aqB0 = *(const bf16x8*)(qbB + (size_t)l15 * HEAD + l4 * 8);
  const bf16x8 aqB1 = *(const bf16x8*)(qbB + (size_t)l15 * HEAD + 32 + l4 * 8);

  f32x4 oA[4], oB[4];
  #pragma unroll
  for (int i = 0; i < 4; ++i) {
    oA[i] = (f32x4){0.f, 0.f, 0.f, 0.f};
    oB[i] = (f32x4){0.f, 0.f, 0.f, 0.f};
  }
  float lsA[4] = {0.f, 0.f, 0.f, 0.f};
  float lsB[4] = {0.f, 0.f, 0.f, 0.f};

  for (int t = wave; t < ntiles; t += 4) {
    const int kv0 = t * 64;
    const bool diag = (t == ntiles - 1);

    // --- K frags loaded ONCE, S for BOTH strips ---
    f32x4 sA[4], sB[4];
    #pragma unroll
    for (int nf = 0; nf < 4; ++nf) {
      sA[nf] = (f32x4){0.f, 0.f, 0.f, 0.f};
      sB[nf] = (f32x4){0.f, 0.f, 0.f, 0.f};
    }
    __builtin_amdgcn_s_setprio(1);
    #pragma unroll
    for (int nf = 0; nf < 4; ++nf) {
      const bf16_t* kp = kb + (size_t)(kv0 + nf * 16 + l15) * HEAD + l4 * 8;
      bf16x8 b0 = *(const bf16x8*)kp;
      bf16x8 b1 = *(const bf16x8*)(kp + 32);
      sA[nf] = MFMA_BF16(aqA0, b0, sA[nf]);
      sB[nf] = MFMA_BF16(aqB0, b0, sB[nf]);
      sA[nf] = MFMA_BF16(aqA1, b1, sA[nf]);
      sB[nf] = MFMA_BF16(aqB1, b1, sB[nf]);
    }
    __builtin_amdgcn_s_setprio(0);

    // ---- expA -> P buffer 0 ----
    float tsA[4] = {0.f, 0.f, 0.f, 0.f};
    #pragma unroll
    for (int nf = 0; nf < 4; ++nf) {
      #pragma unroll
      for (int i2 = 0; i2 < 4; ++i2) {
        float e = exp2f(sA[nf][i2]);
        if (diag) {
          const int col = kv0 + nf * 16 + l15;
          const int row = qrowA + l4 * 4 + i2;
          e = (col <= row) ? e : 0.f;
        }
        tsA[i2] += e;
        P[wave][0][l4 * 4 + i2][nf * 16 + l15] = (bf16_t)e;
      }
    }

    // ---- V loads (latency hides under expB) ----
    bf16x8 v0[4], v1[4];
    #pragma unroll
    for (int nf = 0; nf < 4; ++nf) {
      const bf16_t* vp = vb + (size_t)(nf * 16 + l15) * SEQ + kv0 + l4 * 8;
      v0[nf] = *(const bf16x8*)vp;
      v1[nf] = *(const bf16x8*)(vp + 32);
    }

    // ---- expB -> P buffer 1 ----
    float tsB[4] = {0.f, 0.f, 0.f, 0.f};
    #pragma unroll
    for (int nf = 0; nf < 4; ++nf) {
      #pragma unroll
      for (int i2 = 0; i2 < 4; ++i2) {
        float e = exp2f(sB[nf][i2]);
        if (diag) {
          const int col = kv0 + nf * 16 + l15;
          const int row = qrowB + l4 * 4 + i2;
          e = (col <= row) ? e : 0.f;
        }
        tsB[i2] += e;
        P[wave][1][l4 * 4 + i2][nf * 16 + l15] = (bf16_t)e;
      }
    }

    // ---- PV-A ----
    {
      bf16x8 ap0 = *(const bf16x8*)&P[wave][0][l15][l4 * 8];
      bf16x8 ap1 = *(const bf16x8*)&P[wave][0][l15][32 + l4 * 8];
      __builtin_amdgcn_s_setprio(1);
      #pragma unroll
      for (int nf = 0; nf < 4; ++nf) {
        oA[nf] = MFMA_BF16(ap0, v0[nf], oA[nf]);
        oA[nf] = MFMA_BF16(ap1, v1[nf], oA[nf]);
      }
      __builtin_amdgcn_s_setprio(0);
      #pragma unroll
      for (int i2 = 0; i2 < 4; ++i2) lsA[i2] += tsA[i2];
    }
    // ---- PV-B ----
    {
      bf16x8 bp0 = *(const bf16x8*)&P[wave][1][l15][l4 * 8];
      bf16x8 bp1 = *(const bf16x8*)&P[wave][1][l15][32 + l4 * 8];
      __builtin_amdgcn_s_setprio(1);
      #pragma unroll
      for (int nf = 0; nf < 4; ++nf) {
        oB[nf] = MFMA_BF16(bp0, v0[nf], oB[nf]);
        oB[nf] = MFMA_BF16(bp1, v1[nf], oB[nf]);
      }
      __builtin_amdgcn_s_setprio(0);
      #pragma unroll
      for (int i2 = 0; i2 < 4; ++i2) lsB[i2] += tsB[i2];
    }
  }

  // ---- two-pass cross-wave reduce, pass0 = strip 2u, pass1 = 2u+1 ----
  #pragma unroll
  for (int pass = 0; pass < 2; ++pass) {
    #pragma unroll
    for (int i = 0; i < 4; ++i) {
      float v = pass == 0 ? lsA[i] : lsB[i];
      v += __shfl_xor(v, 1);
      v += __shfl_xor(v, 2);
      v += __shfl_xor(v, 4);
      v += __shfl_xor(v, 8);
      if (l15 == 0) lsums[wave][l4 * 4 + i] = v;
    }
    #pragma unroll
    for (int nf = 0; nf < 4; ++nf)
      #pragma unroll
      for (int i = 0; i < 4; ++i)
        olds[wave][l4 * 4 + i][nf * 16 + l15] = pass == 0 ? oA[nf][i] : oB[nf][i];
    __syncthreads();

    {
      const int r = threadIdx.x >> 4, c0 = threadIdx.x & 15;
      const float sum = lsums[0][r] + lsums[1][r] + lsums[2][r] + lsums[3][r];
      const float rinv = 1.0f / sum;
      const int qrow = pass == 0 ? qrowA : qrowB;
      float* ob = out + ((size_t)batch * SEQ + qrow + r) * HEAD;
      #pragma unroll
      for (int j = 0; j < 4; ++j) {
        const int c = c0 + 16 * j;
        float v = olds[0][r][c] + olds[1][r][c] + olds[2][r][c] + olds[3][r][c];
        ob[c] = v * rinv;
      }
    }
    __syncthreads();
  }
}

// ---------------------------------------------------------------------------
extern "C" void kernel_launch(void* const* d_in, const int* in_sizes, int n_in,
                              void* d_out, int out_size, void* d_ws, size_t ws_size,
                              hipStream_t stream)
{
  const float* x  = (const float*)d_in[0];
  const float* Wq = (const float*)d_in[1];
  const float* Wk = (const float*)d_in[2];
  const float* Wv = (const float*)d_in[3];
  float* out = (float*)d_out;

  const size_t SZ_QKV = (size_t)BATCH * SEQ * HEAD * sizeof(bf16_t);   // 2 MiB
  if (ws_size < 3 * SZ_QKV + (size_t)192 * EMB * sizeof(bf16_t)) return;
  char* ws = (char*)d_ws;
  bf16_t* qo = (bf16_t*)(ws);
  bf16_t* ko = (bf16_t*)(ws + SZ_QKV);
  bf16_t* vT = (bf16_t*)(ws + 2 * SZ_QKV);
  bf16_t* WT = (bf16_t*)(ws + 3 * SZ_QKV);

  wtrans_kernel<<<dim3(48),  dim3(256), 0, stream>>>(Wq, Wk, Wv, WT);
  qkv_kernel  <<<dim3(256), dim3(512), 0, stream>>>(x, WT, qo, ko, vT);
  attn_kernel <<<dim3(512), dim3(256), 0, stream>>>(qo, ko, vT, out);
}